// Round 1
// baseline (23876.636 us; speedup 1.0000x reference)
//
#include <hip/hip_runtime.h>
#include <hip/hip_cooperative_groups.h>

namespace cg = cooperative_groups;

// Problem constants (fixed by the reference)
#define B_  64
#define L_  128
#define H_  1024
#define G4_ 4096
#define T_  256

// ---------------------------------------------------------------------------
// Kernel 1: hidden[b][j] = b_lin[j] + sum_l latent[b][l] * W_lin[j][l]
// One wave per 64 outputs; lane-split dot over L=128 (float2 per lane).
// ---------------------------------------------------------------------------
__global__ void hidden_kernel(const float* __restrict__ latent,
                              const float* __restrict__ W_lin,
                              const float* __restrict__ b_lin,
                              float* __restrict__ hidden) {
    const int wave = (blockIdx.x * blockDim.x + threadIdx.x) >> 6;  // 1024 waves
    const int lane = threadIdx.x & 63;
    for (int o = 0; o < 64; ++o) {
        const int out = wave * 64 + o;              // 65536 outputs
        const int b = out >> 10, j = out & 1023;
        const float2 wv = *(const float2*)(W_lin + j * L_ + lane * 2);
        const float2 xv = *(const float2*)(latent + b * L_ + lane * 2);
        float p = wv.x * xv.x + wv.y * xv.y;
        #pragma unroll
        for (int m = 1; m < 64; m <<= 1) p += __shfl_xor(p, m);
        if (lane == 0) hidden[out] = p + b_lin[j];
    }
}

// ---------------------------------------------------------------------------
// Kernel 2: x_gates[b][j] = b_ih[j] + b_hh[j] + sum_k hidden[b][k]*W_ih[j][k]
// One wave per 64 outputs; lane-split dot over H=1024 (4x float4 per lane).
// W_ih rows read coalesced, one pass over the 16 MB.
// ---------------------------------------------------------------------------
__global__ void xgates_kernel(const float* __restrict__ hidden,
                              const float* __restrict__ W_ih,
                              const float* __restrict__ b_ih,
                              const float* __restrict__ b_hh,
                              float* __restrict__ x_gates) {
    const int wave = (blockIdx.x * blockDim.x + threadIdx.x) >> 6;  // 4096 waves
    const int lane = threadIdx.x & 63;
    for (int o = 0; o < 64; ++o) {
        const int out = wave * 64 + o;              // 262144 outputs
        const int b = out >> 12, j = out & 4095;
        float p = 0.f;
        #pragma unroll
        for (int q = 0; q < 4; ++q) {
            const float4 wv = *(const float4*)(W_ih + j * H_ + q * 256 + lane * 4);
            const float4 hv = *(const float4*)(hidden + b * H_ + q * 256 + lane * 4);
            p += wv.x * hv.x + wv.y * hv.y + wv.z * hv.z + wv.w * hv.w;
        }
        #pragma unroll
        for (int m = 1; m < 64; m <<= 1) p += __shfl_xor(p, m);
        if (lane == 0) x_gates[out] = p + b_ih[j] + b_hh[j];
    }
}

// ---------------------------------------------------------------------------
// Kernel 3: the sequential LSTM. Cooperative launch, 256 WGs x 256 threads.
// WG w owns h indices [4w, 4w+4) -> 16 gate rows (i/f/g/o x 4), kept in VGPRs.
// Thread (ks=tid&15, r=tid>>4): 64 weights of row r, k-slice [64ks, 64ks+64).
// Per step: stage h in 8-batch LDS chunks, register-dot + shfl reduce over ks,
// elementwise in a (hi=tid&3, b=tid>>2) mapping with c persistent in regs.
// One grid.sync() per step; h double-buffered in global scratch.
// ---------------------------------------------------------------------------
__global__ void __launch_bounds__(256, 1)
lstm_kernel(const float* __restrict__ W_hh,     // [4096][1024]
            const float* __restrict__ x_gates,  // [64][4096]
            const float* __restrict__ W_out,    // [1][1024]
            float* __restrict__ h_buf,          // [2][64][1024]
            float* __restrict__ part)           // [T][256][64]
{
    cg::grid_group grid = cg::this_grid();
    const int w   = blockIdx.x;       // 0..255: h-slice owner
    const int tid = threadIdx.x;
    const int ks  = tid & 15;         // k-slice 0..15
    const int r   = tid >> 4;         // local row 0..15  (gate = r>>2, hi = r&3)
    const int c7  = ks & 7;           // xor stagger to spread LDS banks

    __shared__ float Hc[8 * H_];      // 32 KB: 8-batch h chunk (linear)
    __shared__ float Gl[16][66];      // gate dots, padded

    // --- load this thread's 64 weights, pre-permuted to match the xor read order
    const int grow = (r >> 2) * H_ + w * 4 + (r & 3);   // global gate row
    float4 wreg[16];
    #pragma unroll
    for (int i = 0; i < 16; ++i) {
        const int idx = i ^ c7;
        wreg[i] = *(const float4*)(W_hh + (size_t)grow * H_ + ks * 64 + 4 * idx);
    }

    // --- elementwise-phase constants (mapping: hi = tid&3, bb = tid>>2)
    const int hi = tid & 3;
    const int bb = tid >> 2;
    const float xg_i = x_gates[bb * G4_ + 0 * H_ + w * 4 + hi];
    const float xg_f = x_gates[bb * G4_ + 1 * H_ + w * 4 + hi];
    const float xg_g = x_gates[bb * G4_ + 2 * H_ + w * 4 + hi];
    const float xg_o = x_gates[bb * G4_ + 3 * H_ + w * 4 + hi];
    const float wout = W_out[w * 4 + hi];
    float c_state = 0.f;

    // --- zero h_buf[0] (ws is poisoned before every call)
    h_buf[w * 256 + tid] = 0.f;       // 65536 threads cover 64*1024 floats
    grid.sync();

    int cur = 0;
    for (int t = 0; t < T_; ++t) {
        const float* hprev = h_buf + cur * (B_ * H_);

        for (int ch = 0; ch < 8; ++ch) {          // 8 chunks x 8 batches
            __syncthreads();
            // stage 8 batches x 1024 floats, coalesced
            {
                const float4* src = (const float4*)(hprev + ch * 8 * H_);
                float4* dst = (float4*)Hc;
                #pragma unroll
                for (int i = 0; i < 8; ++i)
                    dst[tid + i * 256] = src[tid + i * 256];
            }
            __syncthreads();
            // register dots: 8 batches
            for (int bl = 0; bl < 8; ++bl) {
                const float4* hb = (const float4*)(Hc + bl * H_) + ks * 16;
                float acc = 0.f;
                #pragma unroll
                for (int i = 0; i < 16; ++i) {
                    const float4 hv = hb[i ^ c7];
                    const float4 wv = wreg[i];
                    acc += wv.x * hv.x + wv.y * hv.y + wv.z * hv.z + wv.w * hv.w;
                }
                acc += __shfl_xor(acc, 1);
                acc += __shfl_xor(acc, 2);
                acc += __shfl_xor(acc, 4);
                acc += __shfl_xor(acc, 8);
                if (ks == 0) Gl[r][ch * 8 + bl] = acc;
            }
        }
        __syncthreads();

        // elementwise: thread (hi, bb) owns one (h-index, batch) cell
        {
            const float gi = xg_i + Gl[hi     ][bb];
            const float gf = xg_f + Gl[4  + hi][bb];
            const float gg = xg_g + Gl[8  + hi][bb];
            const float go = xg_o + Gl[12 + hi][bb];
            const float i_ = 1.f / (1.f + expf(-gi));
            const float f_ = 1.f / (1.f + expf(-gf));
            const float g_ = tanhf(gg);
            const float o_ = 1.f / (1.f + expf(-go));
            c_state = f_ * c_state + i_ * g_;
            const float hv = o_ * tanhf(c_state);
            h_buf[(cur ^ 1) * (B_ * H_) + bb * H_ + w * 4 + hi] = hv;
            // output-head partial: sum over this WG's 4 h-indices
            float p = hv * wout;
            p += __shfl_xor(p, 1);
            p += __shfl_xor(p, 2);
            if (hi == 0) part[((size_t)t * 256 + w) * 64 + bb] = p;
        }
        cur ^= 1;
        grid.sync();
    }
}

// ---------------------------------------------------------------------------
// Kernel 4: out[b][t] = b_out + sum_w part[t][w][b]
// ---------------------------------------------------------------------------
__global__ void out_kernel(const float* __restrict__ part,
                           const float* __restrict__ b_out,
                           float* __restrict__ out) {
    const int g = blockIdx.x * blockDim.x + threadIdx.x;  // 16384
    const int t = g >> 6, b = g & 63;
    float s = 0.f;
    for (int w = 0; w < 256; ++w)
        s += part[((size_t)t * 256 + w) * 64 + b];
    out[b * T_ + t] = s + b_out[0];
}

// ---------------------------------------------------------------------------
extern "C" void kernel_launch(void* const* d_in, const int* in_sizes, int n_in,
                              void* d_out, int out_size, void* d_ws, size_t ws_size,
                              hipStream_t stream) {
    const float* latent = (const float*)d_in[0];
    const float* W_lin  = (const float*)d_in[1];
    const float* b_lin  = (const float*)d_in[2];
    const float* W_ih   = (const float*)d_in[3];
    const float* W_hh   = (const float*)d_in[4];
    const float* b_ih   = (const float*)d_in[5];
    const float* b_hh   = (const float*)d_in[6];
    const float* W_out  = (const float*)d_in[7];
    const float* b_out  = (const float*)d_in[8];
    // d_in[9] = seq_len (=256, compile-time T_)

    float* ws      = (float*)d_ws;
    float* hidden  = ws;                   // 65536
    float* x_gates = hidden  + 65536;      // 262144
    float* h_buf   = x_gates + 262144;     // 131072
    float* part    = h_buf   + 131072;     // 4194304  (~18.6 MB total)
    float* out     = (float*)d_out;

    hidden_kernel<<<256, 256, 0, stream>>>(latent, W_lin, b_lin, hidden);
    xgates_kernel<<<1024, 256, 0, stream>>>(hidden, W_ih, b_ih, b_hh, x_gates);

    void* args[] = { (void*)&W_hh, (void*)&x_gates, (void*)&W_out,
                     (void*)&h_buf, (void*)&part };
    hipLaunchCooperativeKernel(reinterpret_cast<void*>(lstm_kernel),
                               dim3(256), dim3(256), args, 0, stream);

    out_kernel<<<64, 256, 0, stream>>>(part, b_out, out);
}

// Round 2
// 12160.812 us; speedup vs baseline: 1.9634x; 1.9634x over previous
//
#include <hip/hip_runtime.h>
#include <hip/hip_cooperative_groups.h>

namespace cg = cooperative_groups;

#define B_  64
#define L_  128
#define H_  1024
#define G4_ 4096
#define T_  256

// ---------------------------------------------------------------------------
// Kernel 1: hidden[b][j] = b_lin[j] + sum_l latent[b][l] * W_lin[j][l]
// ---------------------------------------------------------------------------
__global__ void hidden_kernel(const float* __restrict__ latent,
                              const float* __restrict__ W_lin,
                              const float* __restrict__ b_lin,
                              float* __restrict__ hidden) {
    const int wave = (blockIdx.x * blockDim.x + threadIdx.x) >> 6;
    const int lane = threadIdx.x & 63;
    for (int o = 0; o < 64; ++o) {
        const int out = wave * 64 + o;
        const int b = out >> 10, j = out & 1023;
        const float2 wv = *(const float2*)(W_lin + j * L_ + lane * 2);
        const float2 xv = *(const float2*)(latent + b * L_ + lane * 2);
        float p = wv.x * xv.x + wv.y * xv.y;
        #pragma unroll
        for (int m = 1; m < 64; m <<= 1) p += __shfl_xor(p, m);
        if (lane == 0) hidden[out] = p + b_lin[j];
    }
}

// ---------------------------------------------------------------------------
// Kernel 2: x_gates[b][j] = b_ih[j] + b_hh[j] + sum_k hidden[b][k]*W_ih[j][k]
// ---------------------------------------------------------------------------
__global__ void xgates_kernel(const float* __restrict__ hidden,
                              const float* __restrict__ W_ih,
                              const float* __restrict__ b_ih,
                              const float* __restrict__ b_hh,
                              float* __restrict__ x_gates) {
    const int wave = (blockIdx.x * blockDim.x + threadIdx.x) >> 6;
    const int lane = threadIdx.x & 63;
    for (int o = 0; o < 64; ++o) {
        const int out = wave * 64 + o;
        const int b = out >> 12, j = out & 4095;
        float p = 0.f;
        #pragma unroll
        for (int q = 0; q < 4; ++q) {
            const float4 wv = *(const float4*)(W_ih + j * H_ + q * 256 + lane * 4);
            const float4 hv = *(const float4*)(hidden + b * H_ + q * 256 + lane * 4);
            p += wv.x * hv.x + wv.y * hv.y + wv.z * hv.z + wv.w * hv.w;
        }
        #pragma unroll
        for (int m = 1; m < 64; m <<= 1) p += __shfl_xor(p, m);
        if (lane == 0) x_gates[out] = p + b_ih[j] + b_hh[j];
    }
}

// ---------------------------------------------------------------------------
// Kernel 3: sequential LSTM. 256 WGs x 1024 threads (16 waves/CU).
// WG w owns h indices [4w,4w+4) -> 16 gate rows. Weights live in LDS,
// transposed [k][row-quad planes] with XOR swizzle k^( (k>>5)&7 ).
// Wave wv = (rg=wv>>3, bg=wv&7): rows rg*8..+8, batches bg*8..+8.
// Lane = (kq=lane>>3, b0=lane&7): k split 8-way, one batch per lane.
// h staged per 256-k chunk in swizzled LDS with register prefetch.
// ---------------------------------------------------------------------------
__global__ void __launch_bounds__(1024, 4)
lstm_kernel(const float* __restrict__ W_hh,     // [4096][1024]
            const float* __restrict__ x_gates,  // [64][4096]
            const float* __restrict__ W_out,    // [1024]
            float* __restrict__ h_buf,          // [2][64][1024]
            float* __restrict__ part)           // [T][256][64]
{
    cg::grid_group grid = cg::this_grid();
    extern __shared__ float smem[];
    float* Wlds = smem;            // 16384 f: 4 planes [rq][1024 kx] of float4(4 rows)
    float* Hcf  = smem + 16384;    // 16384 f: [64 b][64 k4 ^ (b&7)] float4
    float* Gl   = smem + 32768;    // 16 x 72

    const int w    = blockIdx.x;
    const int tid  = threadIdx.x;
    const int lane = tid & 63;
    const int wv   = tid >> 6;     // 0..15
    const int rg   = wv >> 3;      // 0..1 : row half (rows rg*8..+8)
    const int bg   = wv & 7;       // 0..7 : batch group
    const int kq   = lane >> 3;    // 0..7 : k slice
    const int b0   = lane & 7;
    const int b    = bg * 8 + b0;

    float4* Wlds4 = (float4*)Wlds;
    float4* Hc4   = (float4*)Hcf;

    // ---- one-time: W_hh slice -> LDS, transposed + swizzled
    {
        const int r_loc = tid >> 6;          // 0..15 = gate*4 + hi
        const int seg   = tid & 63;
        const int gg = r_loc >> 2, hh = r_loc & 3;
        const float* src = W_hh + ((size_t)(gg * H_ + w * 4 + hh)) * H_;
        const int rq = r_loc >> 2, rr = r_loc & 3;   // row-quad == gate
        #pragma unroll
        for (int i4 = 0; i4 < 4; ++i4) {
            float4 v = *(const float4*)(src + seg * 16 + i4 * 4);
            #pragma unroll
            for (int j = 0; j < 4; ++j) {
                const int k  = seg * 16 + i4 * 4 + j;
                const int kx = k ^ ((k >> 5) & 7);
                Wlds[rq * 4096 + kx * 4 + rr] = ((const float*)&v)[j];
            }
        }
    }

    // ---- elementwise-phase constants (threads 0..255: hi=t&3, bb=t>>2)
    const int hi = tid & 3, bb = tid >> 2;
    float xg0 = 0.f, xg1 = 0.f, xg2 = 0.f, xg3 = 0.f, wout = 0.f;
    if (tid < 256) {
        xg0 = x_gates[bb * G4_ + 0 * H_ + w * 4 + hi];
        xg1 = x_gates[bb * G4_ + 1 * H_ + w * 4 + hi];
        xg2 = x_gates[bb * G4_ + 2 * H_ + w * 4 + hi];
        xg3 = x_gates[bb * G4_ + 3 * H_ + w * 4 + hi];
        wout = W_out[w * 4 + hi];
    }
    float c_state = 0.f;

    // ---- zero h_buf[0] (ws poisoned each call)
    {
        const int gt = w * 1024 + tid;
        if (gt < B_ * H_) h_buf[gt] = 0.f;
    }
    __syncthreads();
    grid.sync();

    // staging mapping: thread -> (batch row sb, 16-float segment seg16)
    const int sb    = tid >> 4;     // 0..63
    const int seg16 = tid & 15;
    const int bsw   = sb & 7;

    int cur = 0;
    for (int t = 0; t < T_; ++t) {
        const float* hprev = h_buf + cur * (B_ * H_);
        float4 accA = make_float4(0.f, 0.f, 0.f, 0.f);
        float4 accB = make_float4(0.f, 0.f, 0.f, 0.f);

        // prefetch chunk 0 into registers
        float4 pf0, pf1, pf2, pf3, qf0, qf1, qf2, qf3;
        {
            const float4* s = (const float4*)(hprev + sb * H_ + seg16 * 16);
            pf0 = s[0]; pf1 = s[1]; pf2 = s[2]; pf3 = s[3];
        }

        #pragma unroll
        for (int c = 0; c < 4; ++c) {
            __syncthreads();                     // Hc free to overwrite
            // store prefetched chunk -> Hc (swizzled)
            if ((c & 1) == 0) {
                Hc4[sb * 64 + ((seg16 * 4 + 0) ^ bsw)] = pf0;
                Hc4[sb * 64 + ((seg16 * 4 + 1) ^ bsw)] = pf1;
                Hc4[sb * 64 + ((seg16 * 4 + 2) ^ bsw)] = pf2;
                Hc4[sb * 64 + ((seg16 * 4 + 3) ^ bsw)] = pf3;
            } else {
                Hc4[sb * 64 + ((seg16 * 4 + 0) ^ bsw)] = qf0;
                Hc4[sb * 64 + ((seg16 * 4 + 1) ^ bsw)] = qf1;
                Hc4[sb * 64 + ((seg16 * 4 + 2) ^ bsw)] = qf2;
                Hc4[sb * 64 + ((seg16 * 4 + 3) ^ bsw)] = qf3;
            }
            __syncthreads();                     // Hc ready
            // issue next-chunk prefetch (overlaps compute below)
            if (c < 3) {
                const float4* s = (const float4*)(hprev + sb * H_ + (c + 1) * 256 + seg16 * 16);
                if ((c & 1) == 0) { qf0 = s[0]; qf1 = s[1]; qf2 = s[2]; qf3 = s[3]; }
                else             { pf0 = s[0]; pf1 = s[1]; pf2 = s[2]; pf3 = s[3]; }
            }
            // compute chunk c
            {
                const float4* Hb = Hc4 + b * 64 + kq * 8;
                const float4* WA = Wlds4 + (rg * 2    ) * 1024;
                const float4* WB = Wlds4 + (rg * 2 + 1) * 1024;
                const int kbase = c * 256 + kq * 32;
                const int sw    = (c * 8 + kq) & 7;
                #pragma unroll
                for (int i = 0; i < 8; ++i) {
                    const float4 h4 = Hb[i ^ b0];
                    #pragma unroll
                    for (int j = 0; j < 4; ++j) {
                        const int kx = kbase + ((i * 4 + j) ^ sw);
                        const float4 wA = WA[kx];
                        const float4 wB = WB[kx];
                        const float hj = (j == 0) ? h4.x : (j == 1) ? h4.y
                                        : (j == 2) ? h4.z : h4.w;
                        accA.x += wA.x * hj; accA.y += wA.y * hj;
                        accA.z += wA.z * hj; accA.w += wA.w * hj;
                        accB.x += wB.x * hj; accB.y += wB.y * hj;
                        accB.z += wB.z * hj; accB.w += wB.w * hj;
                    }
                }
            }
        }

        // reduce over kq (lanes stride 8): butterfly
        #pragma unroll
        for (int m = 8; m <= 32; m <<= 1) {
            accA.x += __shfl_xor(accA.x, m); accA.y += __shfl_xor(accA.y, m);
            accA.z += __shfl_xor(accA.z, m); accA.w += __shfl_xor(accA.w, m);
            accB.x += __shfl_xor(accB.x, m); accB.y += __shfl_xor(accB.y, m);
            accB.z += __shfl_xor(accB.z, m); accB.w += __shfl_xor(accB.w, m);
        }
        if (kq == 0) {
            Gl[(rg * 8 + 0) * 72 + b] = accA.x;
            Gl[(rg * 8 + 1) * 72 + b] = accA.y;
            Gl[(rg * 8 + 2) * 72 + b] = accA.z;
            Gl[(rg * 8 + 3) * 72 + b] = accA.w;
            Gl[(rg * 8 + 4) * 72 + b] = accB.x;
            Gl[(rg * 8 + 5) * 72 + b] = accB.y;
            Gl[(rg * 8 + 6) * 72 + b] = accB.z;
            Gl[(rg * 8 + 7) * 72 + b] = accB.w;
        }
        __syncthreads();

        if (tid < 256) {
            const float gi = xg0 + Gl[(0 * 4 + hi) * 72 + bb];
            const float gf = xg1 + Gl[(1 * 4 + hi) * 72 + bb];
            const float gg = xg2 + Gl[(2 * 4 + hi) * 72 + bb];
            const float go = xg3 + Gl[(3 * 4 + hi) * 72 + bb];
            const float i_ = 1.f / (1.f + expf(-gi));
            const float f_ = 1.f / (1.f + expf(-gf));
            const float g_ = tanhf(gg);
            const float o_ = 1.f / (1.f + expf(-go));
            c_state = f_ * c_state + i_ * g_;
            const float hv = o_ * tanhf(c_state);
            h_buf[(cur ^ 1) * (B_ * H_) + bb * H_ + w * 4 + hi] = hv;
            float p = hv * wout;
            p += __shfl_xor(p, 1);
            p += __shfl_xor(p, 2);
            if (hi == 0) part[((size_t)t * 256 + w) * 64 + bb] = p;
        }
        cur ^= 1;
        grid.sync();
    }
}

// ---------------------------------------------------------------------------
// Kernel 4: out[b][t] = b_out + sum_w part[t][w][b]
// ---------------------------------------------------------------------------
__global__ void out_kernel(const float* __restrict__ part,
                           const float* __restrict__ b_out,
                           float* __restrict__ out) {
    const int g = blockIdx.x * blockDim.x + threadIdx.x;  // 16384
    const int t = g >> 6, b = g & 63;
    float s = 0.f;
    for (int w = 0; w < 256; ++w)
        s += part[((size_t)t * 256 + w) * 64 + b];
    out[b * T_ + t] = s + b_out[0];
}

// ---------------------------------------------------------------------------
extern "C" void kernel_launch(void* const* d_in, const int* in_sizes, int n_in,
                              void* d_out, int out_size, void* d_ws, size_t ws_size,
                              hipStream_t stream) {
    const float* latent = (const float*)d_in[0];
    const float* W_lin  = (const float*)d_in[1];
    const float* b_lin  = (const float*)d_in[2];
    const float* W_ih   = (const float*)d_in[3];
    const float* W_hh   = (const float*)d_in[4];
    const float* b_ih   = (const float*)d_in[5];
    const float* b_hh   = (const float*)d_in[6];
    const float* W_out  = (const float*)d_in[7];
    const float* b_out  = (const float*)d_in[8];

    float* ws      = (float*)d_ws;
    float* hidden  = ws;                   // 65536
    float* x_gates = hidden  + 65536;      // 262144
    float* h_buf   = x_gates + 262144;     // 131072
    float* part    = h_buf   + 131072;     // 4194304

    float* out     = (float*)d_out;

    const size_t lds_bytes = (16384 + 16384 + 16 * 72) * sizeof(float);  // 135680
    hipFuncSetAttribute((const void*)lstm_kernel,
                        hipFuncAttributeMaxDynamicSharedMemorySize,
                        (int)lds_bytes);

    hidden_kernel<<<256, 256, 0, stream>>>(latent, W_lin, b_lin, hidden);
    xgates_kernel<<<1024, 256, 0, stream>>>(hidden, W_ih, b_ih, b_hh, x_gates);

    void* args[] = { (void*)&W_hh, (void*)&x_gates, (void*)&W_out,
                     (void*)&h_buf, (void*)&part };
    hipLaunchCooperativeKernel(reinterpret_cast<void*>(lstm_kernel),
                               dim3(256), dim3(1024), args, lds_bytes, stream);

    out_kernel<<<64, 256, 0, stream>>>(part, b_out, out);
}